// Round 7
// baseline (2706.450 us; speedup 1.0000x reference)
//
#include <hip/hip_runtime.h>

// ---- problem constants ----
#define B_   2048
#define T_   512
#define H_   128
#define G_   512
#define R_   8      // batch rows per block
#define NTHR 512    // 8 symmetric waves; wave wv owns units [wv*16, wv*16+16)

typedef _Float16 f16;
typedef _Float16 f16x8 __attribute__((ext_vector_type(8)));
typedef float    f32x4 __attribute__((ext_vector_type(4)));
typedef int      i32x2 __attribute__((ext_vector_type(2)));

// ---- LDS layout (bytes). h tiles: row stride 256 B, XOR swizzle ((row&7)<<4) ----
#define OFF_W1    0                       // w_ih1 f16 [512][128] swizzled = 131072
#define OFF_RING  131072                  // h1 ring: 4 slots x [8][128] f16 = 8192
#define OFF_HB    139264                  // h2 state: 2 bufs x [8][128] f16 = 4096
#define OFF_XT    143360                  // x tiles: 2 bufs x 8 tok x 128 B = 2048
#define LDS_BYTES 145408

__device__ __forceinline__ float rcp_(float v) {
#if __has_builtin(__builtin_amdgcn_rcpf)
  return __builtin_amdgcn_rcpf(v);
#else
  return 1.0f / v;
#endif
}
__device__ __forceinline__ float sig_(float v)  { return rcp_(1.0f + __expf(-v)); }
__device__ __forceinline__ float tanh_(float v) { return 1.0f - 2.0f * rcp_(__expf(2.0f * v) + 1.0f); }

__device__ __forceinline__ f16x8 cvt8(const float* __restrict__ p) {
  float4 a = ((const float4*)p)[0];
  float4 b = ((const float4*)p)[1];
  f16x8 v;
  v[0]=(f16)a.x; v[1]=(f16)a.y; v[2]=(f16)a.z; v[3]=(f16)a.w;
  v[4]=(f16)b.x; v[5]=(f16)b.y; v[6]=(f16)b.z; v[7]=(f16)b.w;
  return v;
}
__device__ __forceinline__ f32x4 mfma16(f16x8 a, f16x8 b, f32x4 c) {
  return __builtin_amdgcn_mfma_f32_16x16x32_f16(a, b, c, 0, 0, 0);
}

// v_permlane32_swap: x = {a.lo, b.lo} (even-row spread), y = {a.hi, b.hi} (odd)
// HW-validated (rounds 5,6 passed with this path).
__device__ __forceinline__ void pls2_(float a, float b, float& x, float& y) {
#if __has_builtin(__builtin_amdgcn_permlane32_swap)
  i32x2 r = __builtin_amdgcn_permlane32_swap(__float_as_int(a), __float_as_int(b),
                                             false, false);
  x = __int_as_float(r.x); y = __int_as_float(r.y);
#else
  asm volatile("v_permlane32_swap_b32 %0, %1" : "+v"(a), "+v"(b));
  x = a; y = b;
#endif
}

// One pipeline step. SM8 = s mod 8 (compile-time) -> all ring/xT/parity static.
template<int SM8, bool DOL0, bool DOPROJ, bool DOL1>
__device__ __forceinline__ void lstm_step(
    int xbuf, int cc,
    const float* __restrict__ x,
    char* __restrict__ ringB, char* __restrict__ hBB, char* __restrict__ xT,
    const char* __restrict__ w1L,
    int lane, int wv, int n, int hi, int u0, int rsw,
    const int (&offA)[4],
    const f16x8 (&whh0f)[4][4], const f16x8 (&whh1f)[4][4], const f16x8 (&w0p)[4],
    const float (&b0)[4], const float (&bP)[4],
    float& cA0, float& cA1, float& cB0, float& cB1,
    f32x4 (&xpP)[4],
    float& xr0, float& xr1, float& xr2,
    int rowbase, int colb, int blk)
{
  // ---- x staging (wave 7), fires at s%8==3: write chunk cc+1 from regs, load cc+2 ----
  if constexpr (SM8 == 3) {
    if (wv == 7) {
      const int c = cc;
      const int tok = lane >> 3, r = lane & 7;
      if (c <= 61) {
        const size_t base = (size_t)(blk*R_ + r) * T_ + (8*(c+2) + tok);
        const float a0 = x[base*3+0], a1 = x[base*3+1], a2 = x[base*3+2];
        f16* w = (f16*)(xT + ((c+1)&1)*1024 + tok*128 + r*16);
        w[0] = (f16)xr0; w[1] = (f16)xr1; w[2] = (f16)xr2;
        xr0 = a0; xr1 = a1; xr2 = a2;
      } else if (c == 62) {
        f16* w = (f16*)(xT + ((c+1)&1)*1024 + tok*128 + r*16);
        w[0] = (f16)xr0; w[1] = (f16)xr1; w[2] = (f16)xr2;
      }
    }
  }

  // ---- proj: token pair (s-2 -> rows 0-7, s-1 -> rows 8-15), even steps ----
  if constexpr (DOPROJ) {
    const char* pa = ringB + ((n < 8) ? (((SM8+2)&3)*2048) : (((SM8+3)&3)*2048));
    #pragma unroll
    for (int q = 0; q < 4; ++q)
      { xpP[q][0]=bP[q]; xpP[q][1]=bP[q]; xpP[q][2]=bP[q]; xpP[q][3]=bP[q]; }
    #pragma unroll
    for (int kc = 0; kc < 4; ++kc) {
      const f16x8 a = *(const f16x8*)(pa + offA[kc]);
      #pragma unroll
      for (int q = 0; q < 4; ++q) {
        const f16x8 bf = *(const f16x8*)(w1L + (q*H_ + u0 + n)*256
                                         + ((kc*64 + hi*16) ^ rsw));
        xpP[q] = mfma16(a, bf, xpP[q]);
      }
    }
  }

  // ---- layer 0 (token s) ----
  if constexpr (DOL0) {
    const f16x8 ax = *(const f16x8*)(xT + xbuf*1024 + SM8*128 + (n&7)*16);
    f32x4 acc[4];
    #pragma unroll
    for (int q = 0; q < 4; ++q) {
      f32x4 a; a[0]=b0[q]; a[1]=b0[q]; a[2]=b0[q]; a[3]=b0[q];
      acc[q] = mfma16(ax, w0p[q], a);
    }
    const char* pa = ringB + (((SM8+3)&3)*2048);
    #pragma unroll
    for (int kc = 0; kc < 4; ++kc) {
      const f16x8 af = *(const f16x8*)(pa + offA[kc]);
      #pragma unroll
      for (int q = 0; q < 4; ++q) acc[q] = mfma16(af, whh0f[q][kc], acc[q]);
    }
    char* wr = ringB + ((SM8&3)*2048);
    float gA[4], gB[4], d0, d1;
    #pragma unroll
    for (int q = 0; q < 4; ++q) {
      pls2_(acc[q][0], acc[q][2], gA[q], d0);
      pls2_(acc[q][1], acc[q][3], gB[q], d1);
    }
    {
      const float iv = sig_(gA[0]), fv = sig_(gA[1]), gv = tanh_(gA[2]), ov = sig_(gA[3]);
      cA0 = fv*cA0 + iv*gv;
      const float h = ov * tanh_(cA0);
      *(f16*)(wr + rowbase*256 + (colb ^ (rowbase<<4))) = (f16)h;
    }
    {
      const float iv = sig_(gB[0]), fv = sig_(gB[1]), gv = tanh_(gB[2]), ov = sig_(gB[3]);
      cA1 = fv*cA1 + iv*gv;
      const float h = ov * tanh_(cA1);
      *(f16*)(wr + (rowbase+1)*256 + (colb ^ ((rowbase+1)<<4))) = (f16)h;
    }
  }

  // ---- layer 1 (token s-2); odd tokens ride the y-half of the swap (static) ----
  if constexpr (DOL1) {
    const char* pb = hBB + ((SM8&1)*2048);
    f32x4 acc[4];
    #pragma unroll
    for (int q = 0; q < 4; ++q) acc[q] = xpP[q];
    #pragma unroll
    for (int kc = 0; kc < 4; ++kc) {
      const f16x8 af = *(const f16x8*)(pb + offA[kc]);
      #pragma unroll
      for (int q = 0; q < 4; ++q) acc[q] = mfma16(af, whh1f[q][kc], acc[q]);
    }
    char* wr = hBB + (((SM8+1)&1)*2048);
    float gA[4], gB[4];
    #pragma unroll
    for (int q = 0; q < 4; ++q) {
      float ex, ey, fx, fy;
      pls2_(acc[q][0], acc[q][2], ex, ey);
      pls2_(acc[q][1], acc[q][3], fx, fy);
      if constexpr ((SM8 & 1) != 0) { gA[q] = ey; gB[q] = fy; }
      else                          { gA[q] = ex; gB[q] = fx; }
    }
    {
      const float iv = sig_(gA[0]), fv = sig_(gA[1]), gv = tanh_(gA[2]), ov = sig_(gA[3]);
      cB0 = fv*cB0 + iv*gv;
      const float h = ov * tanh_(cB0);
      *(f16*)(wr + rowbase*256 + (colb ^ (rowbase<<4))) = (f16)h;
    }
    {
      const float iv = sig_(gB[0]), fv = sig_(gB[1]), gv = tanh_(gB[2]), ov = sig_(gB[3]);
      cB1 = fv*cB1 + iv*gv;
      const float h = ov * tanh_(cB1);
      *(f16*)(wr + (rowbase+1)*256 + (colb ^ ((rowbase+1)<<4))) = (f16)h;
    }
  }
  __syncthreads();
}

#define CALL_STEP(SM8, L0F, PRJ, L1F, XB, CC) \
  lstm_step<SM8, L0F, PRJ, L1F>((XB), (CC), x, ringB, hBB, xT, w1L, \
      lane, wv, n, hi, u0, rsw, offA, whh0f, whh1f, w0p, b0, bP, \
      cA0, cA1, cB0, cB1, xpP, xr0, xr1, xr2, rowbase, colb, blk)

__global__ __launch_bounds__(NTHR, 2)
void lstm_v7(const float* __restrict__ x,
             const float* __restrict__ w_ih0, const float* __restrict__ w_hh0,
             const float* __restrict__ b_ih0, const float* __restrict__ b_hh0,
             const float* __restrict__ w_ih1, const float* __restrict__ w_hh1,
             const float* __restrict__ b_ih1, const float* __restrict__ b_hh1,
             const float* __restrict__ fc_w,  const float* __restrict__ fc_b,
             float* __restrict__ out)
{
  extern __shared__ char lds[];
  char*  w1L   = lds + OFF_W1;
  char*  ringB = lds + OFF_RING;
  char*  hBB   = lds + OFF_HB;
  char*  xT    = lds + OFF_XT;

  const int tid  = (int)threadIdx.x;
  const int lane = tid & 63;
  const int wv   = tid >> 6;
  const int n    = lane & 15;
  const int hi   = lane >> 4;
  const int u0   = wv * 16;
  const int blk  = (int)blockIdx.x;
  const int rsw  = (n & 7) << 4;

  // ---- stage w_ih1 -> LDS f16, swizzled ----
  for (int idx = tid; idx < G_*16; idx += NTHR) {
    const int g = idx >> 4, s7 = idx & 15;
    f16x8 v = cvt8(w_ih1 + g*H_ + s7*8);
    *(f16x8*)(w1L + g*256 + ((s7*16) ^ ((g&7)<<4))) = v;
  }
  // zero ring + hB + xT (14336 B = 3584 dwords); xT pad must stay finite
  for (int i = tid; i < 3584; i += NTHR) ((unsigned*)ringB)[i] = 0u;
  __syncthreads();

  // ---- wave 7: x prologue (chunk 0 -> xT buf0; chunk 1 -> regs) ----
  float xr0 = 0.f, xr1 = 0.f, xr2 = 0.f;
  if (wv == 7) {
    const int tok = lane >> 3, r = lane & 7;
    const size_t base = (size_t)(blk*R_ + r) * T_;
    const float a0 = x[(base + tok)*3+0];
    const float a1 = x[(base + tok)*3+1];
    const float a2 = x[(base + tok)*3+2];
    f16* w = (f16*)(xT + tok*128 + r*16);
    w[0] = (f16)a0; w[1] = (f16)a1; w[2] = (f16)a2;
    xr0 = x[(base + 8 + tok)*3+0];
    xr1 = x[(base + 8 + tok)*3+1];
    xr2 = x[(base + 8 + tok)*3+2];
  }

  // ---- resident weight fragments: 128 VGPRs (proven budget) ----
  f16x8 whh0f[4][4], whh1f[4][4];
  #pragma unroll
  for (int q = 0; q < 4; ++q)
    #pragma unroll
    for (int kc = 0; kc < 4; ++kc) {
      const int off = (q*H_ + u0 + n)*H_ + kc*32 + hi*8;
      whh0f[q][kc] = cvt8(w_hh0 + off);
      whh1f[q][kc] = cvt8(w_hh1 + off);
    }
  // padded w_ih0 B-frags (K=32; k>=3 zero; only hi==0 lanes carry data)
  f16x8 w0p[4];
  float b0[4], bP[4];
  #pragma unroll
  for (int q = 0; q < 4; ++q) {
    const int g = q*H_ + u0 + n;
    b0[q] = b_ih0[g] + b_hh0[g];
    bP[q] = b_ih1[g] + b_hh1[g];
    f16x8 z;
    #pragma unroll
    for (int e = 0; e < 8; ++e) z[e] = (f16)0.f;
    if (hi == 0) {
      z[0] = (f16)w_ih0[g*3+0];
      z[1] = (f16)w_ih0[g*3+1];
      z[2] = (f16)w_ih0[g*3+2];
    }
    w0p[q] = z;
  }

  int offA[4];
  #pragma unroll
  for (int kc = 0; kc < 4; ++kc)
    offA[kc] = (n&7)*256 + ((kc*64 + hi*16) ^ rsw);

  float cA0 = 0.f, cA1 = 0.f, cB0 = 0.f, cB1 = 0.f;
  f32x4 xpP[4];
  const int rowbase = (hi & 1)*4 + ((lane >= 32) ? 2 : 0);
  const int colb    = 2*(u0 + n);
  __syncthreads();

  // ---- prologue: s = 0, 1 (L0 only) ----
  CALL_STEP(0, true, false, false, 0, 0);
  CALL_STEP(1, true, false, false, 0, 0);

  // ---- main: s = 2..505, 63 iterations x 8 steps, all addresses static ----
  for (int m = 0; m < 63; ++m) {
    const int mb = m & 1, mb1 = mb ^ 1;
    CALL_STEP(2, true, true,  true, mb,  0);   // s = 8m+2
    CALL_STEP(3, true, false, true, mb,  m);   // s = 8m+3 (x staging, c=m)
    CALL_STEP(4, true, true,  true, mb,  0);
    CALL_STEP(5, true, false, true, mb,  0);
    CALL_STEP(6, true, true,  true, mb,  0);
    CALL_STEP(7, true, false, true, mb,  0);
    CALL_STEP(0, true, true,  true, mb1, 0);   // s = 8m+8
    CALL_STEP(1, true, false, true, mb1, 0);   // s = 8m+9
  }

  // ---- epilogue: s = 506..513, fully peeled static ----
  CALL_STEP(2, true,  true,  true, 1, 0);    // 506
  CALL_STEP(3, true,  false, true, 1, 63);   // 507 (staging no-op at c=63)
  CALL_STEP(4, true,  true,  true, 1, 0);    // 508
  CALL_STEP(5, true,  false, true, 1, 0);    // 509
  CALL_STEP(6, true,  true,  true, 1, 0);    // 510
  CALL_STEP(7, true,  false, true, 1, 0);    // 511 (last L0)
  CALL_STEP(0, false, true,  true, 0, 0);    // 512 (proj tokens 510,511)
  CALL_STEP(1, false, false, true, 0, 0);    // 513 (last L1; final h2 -> buf0)

  // ---- FC head: final h2 in hBB buf0 ----
  if (tid < R_*2) {
    const int r = tid >> 1, o = tid & 1;
    float acc = fc_b[o];
    #pragma unroll 4
    for (int d = 0; d < H_; ++d) {
      const f16 hv = *(const f16*)(hBB + r*256 + ((2*d) ^ ((r&7)<<4)));
      acc += (float)hv * fc_w[o*H_ + d];
    }
    out[(blk*R_ + r)*2 + o] = acc;
  }
}

extern "C" void kernel_launch(void* const* d_in, const int* in_sizes, int n_in,
                              void* d_out, int out_size, void* d_ws, size_t ws_size,
                              hipStream_t stream) {
  const float* x     = (const float*)d_in[0];
  const float* w_ih0 = (const float*)d_in[1];
  const float* w_hh0 = (const float*)d_in[2];
  const float* b_ih0 = (const float*)d_in[3];
  const float* b_hh0 = (const float*)d_in[4];
  const float* w_ih1 = (const float*)d_in[5];
  const float* w_hh1 = (const float*)d_in[6];
  const float* b_ih1 = (const float*)d_in[7];
  const float* b_hh1 = (const float*)d_in[8];
  const float* fc_w  = (const float*)d_in[9];
  const float* fc_b  = (const float*)d_in[10];
  (void)in_sizes; (void)n_in; (void)out_size; (void)d_ws; (void)ws_size;

  hipFuncSetAttribute((const void*)lstm_v7,
                      hipFuncAttributeMaxDynamicSharedMemorySize, LDS_BYTES);

  lstm_v7<<<B_/R_, NTHR, LDS_BYTES, stream>>>(
      x, w_ih0, w_hh0, b_ih0, b_hh0, w_ih1, w_hh1, b_ih1, b_hh1,
      fc_w, fc_b, (float*)d_out);
}

// Round 8
// 1183.484 us; speedup vs baseline: 2.2869x; 2.2869x over previous
//
#include <hip/hip_runtime.h>

// ---- problem constants ----
#define B_   2048
#define T_   512
#define H_   128
#define G_   512
#define R_   8      // batch rows per block
#define NTHR 512    // 8 symmetric waves; wave wv owns units [wv*16, wv*16+16)

typedef _Float16 f16;
typedef _Float16 f16x8 __attribute__((ext_vector_type(8)));
typedef float    f32x4 __attribute__((ext_vector_type(4)));
typedef int      i32x2 __attribute__((ext_vector_type(2)));

// ---- LDS layout (bytes). h tiles: row stride 256 B, XOR swizzle ((row&7)<<4) ----
#define OFF_W1    0                       // w_ih1 f16 [512][128] swizzled = 131072
#define OFF_RING  131072                  // h1 ring: 8 slots x [8][128] f16 = 16384
#define OFF_HB    147456                  // h2 state: 2 bufs x [8][128] f16 = 4096
#define OFF_XT    151552                  // x tiles: 2 bufs x 8 tok x 128 B = 2048
#define LDS_BYTES 153600

__device__ __forceinline__ float rcp_(float v) {
#if __has_builtin(__builtin_amdgcn_rcpf)
  return __builtin_amdgcn_rcpf(v);
#else
  return 1.0f / v;
#endif
}
__device__ __forceinline__ float sig_(float v)  { return rcp_(1.0f + __expf(-v)); }
__device__ __forceinline__ float tanh_(float v) { return 1.0f - 2.0f * rcp_(__expf(2.0f * v) + 1.0f); }

__device__ __forceinline__ f16x8 cvt8(const float* __restrict__ p) {
  float4 a = ((const float4*)p)[0];
  float4 b = ((const float4*)p)[1];
  f16x8 v;
  v[0]=(f16)a.x; v[1]=(f16)a.y; v[2]=(f16)a.z; v[3]=(f16)a.w;
  v[4]=(f16)b.x; v[5]=(f16)b.y; v[6]=(f16)b.z; v[7]=(f16)b.w;
  return v;
}
__device__ __forceinline__ f32x4 mfma16(f16x8 a, f16x8 b, f32x4 c) {
  return __builtin_amdgcn_mfma_f32_16x16x32_f16(a, b, c, 0, 0, 0);
}

// v_permlane32_swap: x = {a.lo, b.lo} (even-row spread), y = {a.hi, b.hi} (odd)
// HW-validated (rounds 5,6 passed with this path).
__device__ __forceinline__ void pls2_(float a, float b, float& x, float& y) {
#if __has_builtin(__builtin_amdgcn_permlane32_swap)
  i32x2 r = __builtin_amdgcn_permlane32_swap(__float_as_int(a), __float_as_int(b),
                                             false, false);
  x = __int_as_float(r.x); y = __int_as_float(r.y);
#else
  asm volatile("v_permlane32_swap_b32 %0, %1" : "+v"(a), "+v"(b));
  x = a; y = b;
#endif
}

// Pack this lane's h (f16, RTN) with partner lane (lane^1) via DPP quad_perm.
// Even lanes end with {self, partner} = columns (n, n+1) in one dword.
__device__ __forceinline__ unsigned packpair_(float h) {
  const f16 hf = (f16)h;                       // RTN
  unsigned u = (unsigned)__builtin_bit_cast(unsigned short, hf);
#if __has_builtin(__builtin_amdgcn_mov_dpp)
  unsigned p = (unsigned)__builtin_amdgcn_mov_dpp((int)u, 0xB1, 0xF, 0xF, true);
#else
  unsigned p = (unsigned)__shfl_xor((int)u, 1);
#endif
  return u | (p << 16);
}

__global__ __launch_bounds__(NTHR, 2)
void lstm_v8(const float* __restrict__ x,
             const float* __restrict__ w_ih0, const float* __restrict__ w_hh0,
             const float* __restrict__ b_ih0, const float* __restrict__ b_hh0,
             const float* __restrict__ w_ih1, const float* __restrict__ w_hh1,
             const float* __restrict__ b_ih1, const float* __restrict__ b_hh1,
             const float* __restrict__ fc_w,  const float* __restrict__ fc_b,
             float* __restrict__ out)
{
  extern __shared__ char lds[];
  char*  w1L   = lds + OFF_W1;
  char*  ringB = lds + OFF_RING;
  char*  hBB   = lds + OFF_HB;
  char*  xT    = lds + OFF_XT;

  const int tid  = (int)threadIdx.x;
  const int lane = tid & 63;
  const int wv   = tid >> 6;
  const int n    = lane & 15;
  const int hi   = lane >> 4;
  const int u0   = wv * 16;
  const int blk  = (int)blockIdx.x;
  const int rsw  = (n & 7) << 4;

  // ---- stage w_ih1 -> LDS f16, swizzled ----
  for (int idx = tid; idx < G_*16; idx += NTHR) {
    const int g = idx >> 4, s7 = idx & 15;
    f16x8 v = cvt8(w_ih1 + g*H_ + s7*8);
    *(f16x8*)(w1L + g*256 + ((s7*16) ^ ((g&7)<<4))) = v;
  }
  // zero ring + hB + xT (22528 B = 5632 dwords); xT pad must stay finite
  for (int i = tid; i < 5632; i += NTHR) ((unsigned*)ringB)[i] = 0u;
  __syncthreads();

  // ---- wave 7: x prologue (chunk 0 -> xT buf0; chunk 1 -> regs) ----
  float xr0 = 0.f, xr1 = 0.f, xr2 = 0.f;
  if (wv == 7) {
    const int tok = lane >> 3, r = lane & 7;
    const size_t base = (size_t)(blk*R_ + r) * T_;
    const float a0 = x[(base + tok)*3+0];
    const float a1 = x[(base + tok)*3+1];
    const float a2 = x[(base + tok)*3+2];
    f16* w = (f16*)(xT + tok*128 + r*16);
    w[0] = (f16)a0; w[1] = (f16)a1; w[2] = (f16)a2;
    xr0 = x[(base + 8 + tok)*3+0];
    xr1 = x[(base + 8 + tok)*3+1];
    xr2 = x[(base + 8 + tok)*3+2];
  }

  // ---- resident weight fragments: 128 VGPRs (proven budget) ----
  f16x8 whh0f[4][4], whh1f[4][4];
  #pragma unroll
  for (int q = 0; q < 4; ++q)
    #pragma unroll
    for (int kc = 0; kc < 4; ++kc) {
      const int off = (q*H_ + u0 + n)*H_ + kc*32 + hi*8;
      whh0f[q][kc] = cvt8(w_hh0 + off);
      whh1f[q][kc] = cvt8(w_hh1 + off);
    }
  // padded w_ih0 B-frags (K=32; k>=3 zero; only hi==0 lanes carry data)
  f16x8 w0p[4];
  float b0[4], bP[4];
  #pragma unroll
  for (int q = 0; q < 4; ++q) {
    const int g = q*H_ + u0 + n;
    b0[q] = b_ih0[g] + b_hh0[g];
    bP[q] = b_ih1[g] + b_hh1[g];
    f16x8 z;
    #pragma unroll
    for (int e = 0; e < 8; ++e) z[e] = (f16)0.f;
    if (hi == 0) {
      z[0] = (f16)w_ih0[g*3+0];
      z[1] = (f16)w_ih0[g*3+1];
      z[2] = (f16)w_ih0[g*3+2];
    }
    w0p[q] = z;
  }

  int offA[4];
  #pragma unroll
  for (int kc = 0; kc < 4; ++kc)
    offA[kc] = (n&7)*256 + ((kc*64 + hi*16) ^ rsw);
  int offB[4];
  #pragma unroll
  for (int kc = 0; kc < 4; ++kc)
    offB[kc] = (kc*64 + hi*16) ^ rsw;

  float cA0 = 0.f, cA1 = 0.f, cB0 = 0.f, cB1 = 0.f;
  f32x4 xpA[4], xpB[4];
  const int rowbase = (hi & 1)*4 + ((lane >= 32) ? 2 : 0);
  const int colb    = 2*(u0 + (n & ~1));   // dword-aligned pair base (cols n, n+1)
  const bool wlane  = ((n & 1) == 0);      // even-n lanes perform packed writes
  __syncthreads();

  // pipeline: L0 token s | proj tokens s-4..s-1 at s%4==0 | L1 token s-4
  for (int s = 0; s < T_ + 4; ++s) {
    // ---- x staging: wave 7, once per 8 steps (write c+1 from regs, load c+2) ----
    if (wv == 7 && (s & 7) == 3) {
      const int c = s >> 3;
      const int tok = lane >> 3, r = lane & 7;
      if (c <= 61) {
        const size_t base = (size_t)(blk*R_ + r) * T_ + (8*(c+2) + tok);
        const float a0 = x[base*3+0], a1 = x[base*3+1], a2 = x[base*3+2];
        f16* w = (f16*)(xT + ((c+1)&1)*1024 + tok*128 + r*16);
        w[0] = (f16)xr0; w[1] = (f16)xr1; w[2] = (f16)xr2;
        xr0 = a0; xr1 = a1; xr2 = a2;
      } else if (c == 62) {
        f16* w = (f16*)(xT + ((c+1)&1)*1024 + tok*128 + r*16);
        w[0] = (f16)xr0; w[1] = (f16)xr1; w[2] = (f16)xr2;
      }
    }

    // ---- proj: 4 tokens (s-4..s-1), two M-tiles, ONE w1L sweep ----
    if ((s & 3) == 0 && s >= 4 && s <= T_) {
      const char* pa0 = ringB + ((n < 8) ? (((s-4)&7)*2048) : (((s-3)&7)*2048));
      const char* pa1 = ringB + ((n < 8) ? (((s-2)&7)*2048) : (((s-1)&7)*2048));
      #pragma unroll
      for (int q = 0; q < 4; ++q) {
        xpA[q][0]=bP[q]; xpA[q][1]=bP[q]; xpA[q][2]=bP[q]; xpA[q][3]=bP[q];
        xpB[q][0]=bP[q]; xpB[q][1]=bP[q]; xpB[q][2]=bP[q]; xpB[q][3]=bP[q];
      }
      #pragma unroll
      for (int kc = 0; kc < 4; ++kc) {
        const f16x8 a0 = *(const f16x8*)(pa0 + offA[kc]);
        const f16x8 a1 = *(const f16x8*)(pa1 + offA[kc]);
        #pragma unroll
        for (int q = 0; q < 4; ++q) {
          const f16x8 bf = *(const f16x8*)(w1L + (q*H_ + u0 + n)*256 + offB[kc]);
          xpA[q] = mfma16(a0, bf, xpA[q]);
          xpB[q] = mfma16(a1, bf, xpB[q]);
        }
      }
    }

    // ---- layer 0 (token s) ----
    if (s < T_) {
      const f16x8 ax = *(const f16x8*)(xT + ((s>>3)&1)*1024 + (s&7)*128 + (n&7)*16);
      f32x4 acc[4];
      #pragma unroll
      for (int q = 0; q < 4; ++q) {
        f32x4 a; a[0]=b0[q]; a[1]=b0[q]; a[2]=b0[q]; a[3]=b0[q];
        acc[q] = mfma16(ax, w0p[q], a);
      }
      const char* pa = ringB + (((s-1)&7)*2048);
      #pragma unroll
      for (int kc = 0; kc < 4; ++kc) {
        const f16x8 af = *(const f16x8*)(pa + offA[kc]);
        #pragma unroll
        for (int q = 0; q < 4; ++q) acc[q] = mfma16(af, whh0f[q][kc], acc[q]);
      }
      char* wr = ringB + ((s&7)*2048);
      float gA[4], gB[4], d0, d1;
      #pragma unroll
      for (int q = 0; q < 4; ++q) {
        pls2_(acc[q][0], acc[q][2], gA[q], d0);
        pls2_(acc[q][1], acc[q][3], gB[q], d1);
      }
      {
        const float iv = sig_(gA[0]), fv = sig_(gA[1]), gv = tanh_(gA[2]), ov = sig_(gA[3]);
        cA0 = fv*cA0 + iv*gv;
        const unsigned pk = packpair_(ov * tanh_(cA0));
        if (wlane)
          *(unsigned*)(wr + rowbase*256 + (colb ^ (rowbase<<4))) = pk;
      }
      {
        const float iv = sig_(gB[0]), fv = sig_(gB[1]), gv = tanh_(gB[2]), ov = sig_(gB[3]);
        cA1 = fv*cA1 + iv*gv;
        const unsigned pk = packpair_(ov * tanh_(cA1));
        if (wlane)
          *(unsigned*)(wr + (rowbase+1)*256 + (colb ^ ((rowbase+1)<<4))) = pk;
      }
    }

    // ---- layer 1 (token s-4); phase p = s&3 selects tile/half statically ----
    if (s >= 4) {
      const int  p   = s & 3;
      const bool odd = (p & 1) != 0;
      const char* pb = hBB + (s&1)*2048;
      f32x4 acc[4];
      if (p < 2) {
        #pragma unroll
        for (int q = 0; q < 4; ++q) acc[q] = xpA[q];
      } else {
        #pragma unroll
        for (int q = 0; q < 4; ++q) acc[q] = xpB[q];
      }
      #pragma unroll
      for (int kc = 0; kc < 4; ++kc) {
        const f16x8 af = *(const f16x8*)(pb + offA[kc]);
        #pragma unroll
        for (int q = 0; q < 4; ++q) acc[q] = mfma16(af, whh1f[q][kc], acc[q]);
      }
      char* wr = hBB + (((s+1)&1)*2048);
      float gA[4], gB[4];
      #pragma unroll
      for (int q = 0; q < 4; ++q) {
        float ex, ey, fx, fy;
        pls2_(acc[q][0], acc[q][2], ex, ey);
        pls2_(acc[q][1], acc[q][3], fx, fy);
        gA[q] = odd ? ey : ex;
        gB[q] = odd ? fy : fx;
      }
      {
        const float iv = sig_(gA[0]), fv = sig_(gA[1]), gv = tanh_(gA[2]), ov = sig_(gA[3]);
        cB0 = fv*cB0 + iv*gv;
        const unsigned pk = packpair_(ov * tanh_(cB0));
        if (wlane)
          *(unsigned*)(wr + rowbase*256 + (colb ^ (rowbase<<4))) = pk;
      }
      {
        const float iv = sig_(gB[0]), fv = sig_(gB[1]), gv = tanh_(gB[2]), ov = sig_(gB[3]);
        cB1 = fv*cB1 + iv*gv;
        const unsigned pk = packpair_(ov * tanh_(cB1));
        if (wlane)
          *(unsigned*)(wr + (rowbase+1)*256 + (colb ^ ((rowbase+1)<<4))) = pk;
      }
    }
    __syncthreads();
  }

  // ---- FC head: final h2 (token 511, written step 515) in hBB buf0 ----
  if (tid < R_*2) {
    const int r = tid >> 1, o = tid & 1;
    float acc = fc_b[o];
    #pragma unroll 4
    for (int d = 0; d < H_; ++d) {
      const f16 hv = *(const f16*)(hBB + r*256 + ((2*d) ^ ((r&7)<<4)));
      acc += (float)hv * fc_w[o*H_ + d];
    }
    out[(blk*R_ + r)*2 + o] = acc;
  }
}

extern "C" void kernel_launch(void* const* d_in, const int* in_sizes, int n_in,
                              void* d_out, int out_size, void* d_ws, size_t ws_size,
                              hipStream_t stream) {
  const float* x     = (const float*)d_in[0];
  const float* w_ih0 = (const float*)d_in[1];
  const float* w_hh0 = (const float*)d_in[2];
  const float* b_ih0 = (const float*)d_in[3];
  const float* b_hh0 = (const float*)d_in[4];
  const float* w_ih1 = (const float*)d_in[5];
  const float* w_hh1 = (const float*)d_in[6];
  const float* b_ih1 = (const float*)d_in[7];
  const float* b_hh1 = (const float*)d_in[8];
  const float* fc_w  = (const float*)d_in[9];
  const float* fc_b  = (const float*)d_in[10];
  (void)in_sizes; (void)n_in; (void)out_size; (void)d_ws; (void)ws_size;

  hipFuncSetAttribute((const void*)lstm_v8,
                      hipFuncAttributeMaxDynamicSharedMemorySize, LDS_BYTES);

  lstm_v8<<<B_/R_, NTHR, LDS_BYTES, stream>>>(
      x, w_ih0, w_hh0, b_ih0, b_hh0, w_ih1, w_hh1, b_ih1, b_hh1,
      fc_w, fc_b, (float*)d_out);
}

// Round 9
// 841.455 us; speedup vs baseline: 3.2164x; 1.4065x over previous
//
#include <hip/hip_runtime.h>

// ---- problem constants ----
#define B_   2048
#define T_   512
#define H_   128
#define G_   512
#define R_   8      // batch rows per block
#define NTHR 512    // 8 symmetric waves; wave wv owns units [wv*16, wv*16+16)

typedef _Float16 f16;
typedef _Float16 f16x8 __attribute__((ext_vector_type(8)));
typedef float    f32x4 __attribute__((ext_vector_type(4)));
typedef int      i32x2 __attribute__((ext_vector_type(2)));

// ---- LDS layout (bytes). h tiles: row stride 256 B, XOR swizzle ((row&7)<<4) ----
#define OFF_W1    0                       // w_ih1 f16 [512][128] swizzled = 131072
#define OFF_RING  131072                  // h1 ring: 4 slots x [8][128] f16 = 8192
#define OFF_HB    139264                  // h2 state: 2 bufs x [8][128] f16 = 4096
#define OFF_XT    143360                  // x tiles: 2 bufs x 8 tok x 128 B = 2048
#define LDS_BYTES 145408

__device__ __forceinline__ float rcp_(float v) {
#if __has_builtin(__builtin_amdgcn_rcpf)
  return __builtin_amdgcn_rcpf(v);
#else
  return 1.0f / v;
#endif
}
__device__ __forceinline__ float sig_(float v)  { return rcp_(1.0f + __expf(-v)); }
__device__ __forceinline__ float tanh_(float v) { return 1.0f - 2.0f * rcp_(__expf(2.0f * v) + 1.0f); }

__device__ __forceinline__ f16x8 cvt8(const float* __restrict__ p) {
  float4 a = ((const float4*)p)[0];
  float4 b = ((const float4*)p)[1];
  f16x8 v;
  v[0]=(f16)a.x; v[1]=(f16)a.y; v[2]=(f16)a.z; v[3]=(f16)a.w;
  v[4]=(f16)b.x; v[5]=(f16)b.y; v[6]=(f16)b.z; v[7]=(f16)b.w;
  return v;
}
__device__ __forceinline__ f32x4 mfma16(f16x8 a, f16x8 b, f32x4 c) {
  return __builtin_amdgcn_mfma_f32_16x16x32_f16(a, b, c, 0, 0, 0);
}

// v_permlane32_swap: x = {a.lo, b.lo} (even-row spread), y = {a.hi, b.hi} (odd)
// HW-validated (rounds 5,6 passed with this path).
__device__ __forceinline__ void pls2_(float a, float b, float& x, float& y) {
#if __has_builtin(__builtin_amdgcn_permlane32_swap)
  i32x2 r = __builtin_amdgcn_permlane32_swap(__float_as_int(a), __float_as_int(b),
                                             false, false);
  x = __int_as_float(r.x); y = __int_as_float(r.y);
#else
  asm volatile("v_permlane32_swap_b32 %0, %1" : "+v"(a), "+v"(b));
  x = a; y = b;
#endif
}

__global__ __launch_bounds__(NTHR, 2)
void lstm_v9(const float* __restrict__ x,
             const float* __restrict__ w_ih0, const float* __restrict__ w_hh0,
             const float* __restrict__ b_ih0, const float* __restrict__ b_hh0,
             const float* __restrict__ w_ih1, const float* __restrict__ w_hh1,
             const float* __restrict__ b_ih1, const float* __restrict__ b_hh1,
             const float* __restrict__ fc_w,  const float* __restrict__ fc_b,
             float* __restrict__ out)
{
  extern __shared__ char lds[];
  char*  w1L   = lds + OFF_W1;
  char*  ringB = lds + OFF_RING;
  char*  hBB   = lds + OFF_HB;
  char*  xT    = lds + OFF_XT;

  const int tid  = (int)threadIdx.x;
  const int lane = tid & 63;
  const int wv   = tid >> 6;
  const int n    = lane & 15;
  const int hi   = lane >> 4;
  const int u0   = wv * 16;
  const int blk  = (int)blockIdx.x;
  const int rsw  = (n & 7) << 4;

  // ---- stage w_ih1 -> LDS f16, swizzled ----
  for (int idx = tid; idx < G_*16; idx += NTHR) {
    const int g = idx >> 4, s7 = idx & 15;
    f16x8 v = cvt8(w_ih1 + g*H_ + s7*8);
    *(f16x8*)(w1L + g*256 + ((s7*16) ^ ((g&7)<<4))) = v;
  }
  // zero ring + hB + xT (14336 B = 3584 dwords); xT pad must stay finite
  for (int i = tid; i < 3584; i += NTHR) ((unsigned*)ringB)[i] = 0u;
  __syncthreads();

  // ---- wave 7: x prologue (chunk 0 -> xT buf0; chunk 1 -> regs) ----
  float xr0 = 0.f, xr1 = 0.f, xr2 = 0.f;
  if (wv == 7) {
    const int tok = lane >> 3, r = lane & 7;
    const size_t base = (size_t)(blk*R_ + r) * T_;
    const float a0 = x[(base + tok)*3+0];
    const float a1 = x[(base + tok)*3+1];
    const float a2 = x[(base + tok)*3+2];
    f16* w = (f16*)(xT + tok*128 + r*16);
    w[0] = (f16)a0; w[1] = (f16)a1; w[2] = (f16)a2;
    xr0 = x[(base + 8 + tok)*3+0];
    xr1 = x[(base + 8 + tok)*3+1];
    xr2 = x[(base + 8 + tok)*3+2];
  }

  // ---- resident weight fragments: 128 VGPRs (proven budget) ----
  f16x8 whh0f[4][4], whh1f[4][4];
  #pragma unroll
  for (int q = 0; q < 4; ++q)
    #pragma unroll
    for (int kc = 0; kc < 4; ++kc) {
      const int off = (q*H_ + u0 + n)*H_ + kc*32 + hi*8;
      whh0f[q][kc] = cvt8(w_hh0 + off);
      whh1f[q][kc] = cvt8(w_hh1 + off);
    }
  // padded w_ih0 B-frags (K=32; k>=3 zero; only hi==0 lanes carry data)
  f16x8 w0p[4];
  float b0[4], bP[4];
  #pragma unroll
  for (int q = 0; q < 4; ++q) {
    const int g = q*H_ + u0 + n;
    b0[q] = b_ih0[g] + b_hh0[g];
    bP[q] = b_ih1[g] + b_hh1[g];
    f16x8 z;
    #pragma unroll
    for (int e = 0; e < 8; ++e) z[e] = (f16)0.f;
    if (hi == 0) {
      z[0] = (f16)w_ih0[g*3+0];
      z[1] = (f16)w_ih0[g*3+1];
      z[2] = (f16)w_ih0[g*3+2];
    }
    w0p[q] = z;
  }

  int offA[4];
  #pragma unroll
  for (int kc = 0; kc < 4; ++kc)
    offA[kc] = (n&7)*256 + ((kc*64 + hi*16) ^ rsw);
  int offB[4];
  #pragma unroll
  for (int kc = 0; kc < 4; ++kc)
    offB[kc] = (kc*64 + hi*16) ^ rsw;

  float cA0 = 0.f, cA1 = 0.f, cB0 = 0.f, cB1 = 0.f;
  f32x4 xpP[4];
  const int rowbase = (hi & 1)*4 + ((lane >= 32) ? 2 : 0);
  const int colb    = 2*(u0 + n);
  // loop-invariant swizzled write offsets (within any 2048-B h tile)
  const int wOff0 = rowbase*256     + (colb ^ (rowbase<<4));
  const int wOff1 = (rowbase+1)*256 + (colb ^ ((rowbase+1)<<4));
  __syncthreads();

  // ---- phase lambdas (runtime s; NO templates -> round-7 spill trap avoided) ----
  auto xstage = [&](int s) {
    if (wv == 7 && (s & 7) == 3) {
      const int c = s >> 3;
      const int tok = lane >> 3, r = lane & 7;
      if (c <= 61) {
        const size_t base = (size_t)(blk*R_ + r) * T_ + (8*(c+2) + tok);
        const float a0 = x[base*3+0], a1 = x[base*3+1], a2 = x[base*3+2];
        f16* w = (f16*)(xT + ((c+1)&1)*1024 + tok*128 + r*16);
        w[0] = (f16)xr0; w[1] = (f16)xr1; w[2] = (f16)xr2;
        xr0 = a0; xr1 = a1; xr2 = a2;
      } else if (c == 62) {
        f16* w = (f16*)(xT + ((c+1)&1)*1024 + tok*128 + r*16);
        w[0] = (f16)xr0; w[1] = (f16)xr1; w[2] = (f16)xr2;
      }
    }
  };

  auto proj = [&](int s) {   // tokens (s-2 -> rows 0-7, s-1 -> rows 8-15), even s
    if ((s & 1) == 0 && s >= 2 && s <= T_) {
      const char* pa = ringB + ((n < 8) ? (((s-2)&3)*2048) : (((s-1)&3)*2048));
      #pragma unroll
      for (int q = 0; q < 4; ++q)
        { xpP[q][0]=bP[q]; xpP[q][1]=bP[q]; xpP[q][2]=bP[q]; xpP[q][3]=bP[q]; }
      #pragma unroll
      for (int kc = 0; kc < 4; ++kc) {
        const f16x8 a = *(const f16x8*)(pa + offA[kc]);
        #pragma unroll
        for (int q = 0; q < 4; ++q) {
          const f16x8 bf = *(const f16x8*)(w1L + (q*H_ + u0 + n)*256 + offB[kc]);
          xpP[q] = mfma16(a, bf, xpP[q]);
        }
      }
    }
  };

  auto l0 = [&](int s) {     // layer 0, token s
    if (s < T_) {
      const f16x8 ax = *(const f16x8*)(xT + ((s>>3)&1)*1024 + (s&7)*128 + (n&7)*16);
      f32x4 acc[4];
      #pragma unroll
      for (int q = 0; q < 4; ++q) {
        f32x4 a; a[0]=b0[q]; a[1]=b0[q]; a[2]=b0[q]; a[3]=b0[q];
        acc[q] = mfma16(ax, w0p[q], a);
      }
      const char* pa = ringB + (((s-1)&3)*2048);
      #pragma unroll
      for (int kc = 0; kc < 4; ++kc) {
        const f16x8 af = *(const f16x8*)(pa + offA[kc]);
        #pragma unroll
        for (int q = 0; q < 4; ++q) acc[q] = mfma16(af, whh0f[q][kc], acc[q]);
      }
      char* wr = ringB + ((s&3)*2048);
      float gA[4], gB[4], d0, d1;
      #pragma unroll
      for (int q = 0; q < 4; ++q) {
        pls2_(acc[q][0], acc[q][2], gA[q], d0);
        pls2_(acc[q][1], acc[q][3], gB[q], d1);
      }
      {
        const float iv = sig_(gA[0]), fv = sig_(gA[1]), gv = tanh_(gA[2]), ov = sig_(gA[3]);
        cA0 = fv*cA0 + iv*gv;
        *(f16*)(wr + wOff0) = (f16)(ov * tanh_(cA0));
      }
      {
        const float iv = sig_(gB[0]), fv = sig_(gB[1]), gv = tanh_(gB[2]), ov = sig_(gB[3]);
        cA1 = fv*cA1 + iv*gv;
        *(f16*)(wr + wOff1) = (f16)(ov * tanh_(cA1));
      }
    }
  };

  auto l1 = [&](int s) {     // layer 1, token s-2; odd tokens ride y-half of swap
    if (s >= 2) {
      const bool odd = (s & 1);
      const char* pb = hBB + (s&1)*2048;
      f32x4 acc[4];
      #pragma unroll
      for (int q = 0; q < 4; ++q) acc[q] = xpP[q];
      #pragma unroll
      for (int kc = 0; kc < 4; ++kc) {
        const f16x8 af = *(const f16x8*)(pb + offA[kc]);
        #pragma unroll
        for (int q = 0; q < 4; ++q) acc[q] = mfma16(af, whh1f[q][kc], acc[q]);
      }
      char* wr = hBB + (((s+1)&1)*2048);
      float gA[4], gB[4];
      #pragma unroll
      for (int q = 0; q < 4; ++q) {
        float ex, ey, fx, fy;
        pls2_(acc[q][0], acc[q][2], ex, ey);
        pls2_(acc[q][1], acc[q][3], fx, fy);
        gA[q] = odd ? ey : ex;
        gB[q] = odd ? fy : fx;
      }
      {
        const float iv = sig_(gA[0]), fv = sig_(gA[1]), gv = tanh_(gA[2]), ov = sig_(gA[3]);
        cB0 = fv*cB0 + iv*gv;
        *(f16*)(wr + wOff0) = (f16)(ov * tanh_(cB0));
      }
      {
        const float iv = sig_(gB[0]), fv = sig_(gB[1]), gv = tanh_(gB[2]), ov = sig_(gB[3]);
        cB1 = fv*cB1 + iv*gv;
        *(f16*)(wr + wOff1) = (f16)(ov * tanh_(cB1));
      }
    }
  };

  // ---- main loop: wave-parity phase stagger breaks the LDS/VALU convoy.
  // All phase inputs are pre-barrier except proj->L1 (same step), preserved
  // in both orders. Writes of different phases go to disjoint LDS regions.
  for (int s = 0; s < T_ + 2; ++s) {
    if (wv & 1) {            // odd waves (incl. wave 7 w/ x staging): L0 first
      xstage(s);
      l0(s);
      proj(s);
      l1(s);
    } else {                 // even waves: proj/L1 first, L0 last
      proj(s);
      l1(s);
      l0(s);
    }
    __syncthreads();
  }

  // ---- FC head: final h2 in hBB buf (T_+2)&1 == 0 ----
  if (tid < R_*2) {
    const int r = tid >> 1, o = tid & 1;
    float acc = fc_b[o];
    #pragma unroll 4
    for (int d = 0; d < H_; ++d) {
      const f16 hv = *(const f16*)(hBB + r*256 + ((2*d) ^ ((r&7)<<4)));
      acc += (float)hv * fc_w[o*H_ + d];
    }
    out[(blk*R_ + r)*2 + o] = acc;
  }
}

extern "C" void kernel_launch(void* const* d_in, const int* in_sizes, int n_in,
                              void* d_out, int out_size, void* d_ws, size_t ws_size,
                              hipStream_t stream) {
  const float* x     = (const float*)d_in[0];
  const float* w_ih0 = (const float*)d_in[1];
  const float* w_hh0 = (const float*)d_in[2];
  const float* b_ih0 = (const float*)d_in[3];
  const float* b_hh0 = (const float*)d_in[4];
  const float* w_ih1 = (const float*)d_in[5];
  const float* w_hh1 = (const float*)d_in[6];
  const float* b_ih1 = (const float*)d_in[7];
  const float* b_hh1 = (const float*)d_in[8];
  const float* fc_w  = (const float*)d_in[9];
  const float* fc_b  = (const float*)d_in[10];
  (void)in_sizes; (void)n_in; (void)out_size; (void)d_ws; (void)ws_size;

  hipFuncSetAttribute((const void*)lstm_v9,
                      hipFuncAttributeMaxDynamicSharedMemorySize, LDS_BYTES);

  lstm_v9<<<B_/R_, NTHR, LDS_BYTES, stream>>>(
      x, w_ih0, w_hh0, b_ih0, b_hh0, w_ih1, w_hh1, b_ih1, b_hh1,
      fc_w, fc_b, (float*)d_out);
}